// Round 24
// baseline (114.800 us; speedup 1.0000x reference)
//
#include <hip/hip_runtime.h>
#include <hip/hip_bf16.h>

#define B_ 4
#define S_ 2048
#define D_ 512
#define H_ 16
#define HD_ 32

typedef __bf16 bf16;
typedef __bf16 bf16x4 __attribute__((ext_vector_type(4)));
typedef __bf16 bf16x8 __attribute__((ext_vector_type(8)));
typedef float f32x4 __attribute__((ext_vector_type(4)));

__device__ __forceinline__ f32x4 mfma16(bf16x8 a, bf16x8 b, f32x4 c) {
  return __builtin_amdgcn_mfma_f32_16x16x32_bf16(a, b, c, 0, 0, 0);
}

// async global->LDS, 16B per lane; lds dest wave-uniform base (HW: +lane*16)
__device__ __forceinline__ void gload16(const bf16* g, bf16* l) {
  __builtin_amdgcn_global_load_lds(
      (const __attribute__((address_space(1))) void*)g,
      (__attribute__((address_space(3))) void*)l, 16, 0, 0);
}

__device__ __forceinline__ bf16x8 cvt8(const float* __restrict__ p) {
  const f32x4* v = (const f32x4*)p;
  f32x4 a = v[0], b = v[1];
  bf16x8 r;
  r[0] = (bf16)a[0]; r[1] = (bf16)a[1]; r[2] = (bf16)a[2]; r[3] = (bf16)a[3];
  r[4] = (bf16)b[0]; r[5] = (bf16)b[1]; r[6] = (bf16)b[2]; r[7] = (bf16)b[3];
  return r;
}

__device__ __forceinline__ bf16x8 pack8(f32x4 a, f32x4 b) {
  bf16x8 r;
  r[0] = (bf16)a[0]; r[1] = (bf16)a[1]; r[2] = (bf16)a[2]; r[3] = (bf16)a[3];
  r[4] = (bf16)b[0]; r[5] = (bf16)b[1]; r[6] = (bf16)b[2]; r[7] = (bf16)b[3];
  return r;
}

// ------- K0: prep (cvt_w + lengths + RoPE cos/sin table; x stays f32) -------
__global__ __launch_bounds__(256) void prep_kernel(
    const float* __restrict__ wq, const float* __restrict__ wk,
    const float* __restrict__ wv, const float* __restrict__ wo,
    const unsigned char* __restrict__ am, const unsigned char* __restrict__ kpm,
    bf16* __restrict__ dq, bf16* __restrict__ dk, bf16* __restrict__ dv,
    bf16* __restrict__ dwo, int* __restrict__ lengths_out,
    float* __restrict__ costab, float* __restrict__ sintab) {
  int bid = blockIdx.x;
  if (bid < 512) {  // weights: 128 blocks per 512x512 matrix
    int mat = bid >> 7;
    size_t i = (size_t)(bid & 127) * 256 + threadIdx.x;
    const float* s = (mat == 0) ? wq : (mat == 1) ? wk : (mat == 2) ? wv : wo;
    bf16* d = (mat == 0) ? dq : (mat == 1) ? dk : (mat == 2) ? dv : dwo;
    *(bf16x8*)(d + i * 8) = cvt8(s + i * 8);
  } else if (bid == 512) {  // lengths: 4 waves, wave b handles batch b
    int b = threadIdx.x >> 6, lane = threadIdx.x & 63;
    int esize;
    if (am[1] == 1) esize = 1;
    else if (am[2] == 0x80 && am[3] == 0x3F) esize = 2;
    else if (am[3] == 0x3C) esize = 2;
    else if (am[4] == 1) esize = 4;
    else if (am[6] == 0x80 && am[7] == 0x3F) esize = 4;
    else if (am[8] == 1) esize = 8;
    else esize = 1;
    int cnt = 0;
    for (int i = lane; i < S_; i += 64) {
      size_t off = ((size_t)b * S_ + i) * (size_t)esize;
      unsigned char nz = 0;
      for (int e = 0; e < esize; ++e) nz |= kpm[off + e];
      cnt += (nz == 0) ? 1 : 0;
    }
    for (int off = 1; off < 64; off <<= 1) cnt += __shfl_xor(cnt, off);
    if (lane == 0) lengths_out[b] = cnt;
  } else {  // RoPE table: [S][16] cos + sin (128 blocks)
    int ti = (bid - 513) * 256 + threadIdx.x;  // < 32768
    int s = ti >> 4, cc = ti & 15;
    float invf = powf(10000.0f, -(float)cc * (1.0f / 16.0f));
    float ang = (float)s * invf;
    costab[ti] = cosf(ang);
    sintab[ti] = sinf(ang);
  }
}

// ---------------- K1: fused QKV GEMM + RoPE (BM=64, 1536 blocks) ------------
__global__ __launch_bounds__(256) void qkv_rope_kernel(
    const float* __restrict__ x, const bf16* __restrict__ Wq,
    const bf16* __restrict__ Wk, const bf16* __restrict__ Wv,
    const float* __restrict__ costab, const float* __restrict__ sintab,
    bf16* __restrict__ q_ws, bf16* __restrict__ k_ws, bf16* __restrict__ vt_ws) {
  __shared__ __align__(16) bf16 smem[12288];  // 24576 B
#define AS(b) (smem + (b) * 2048)            // 64x32 A tile
#define BS(b) (smem + 4096 + (b) * 4096)     // 128x32 B tile
#define CT smem                              // V transpose: 128x72

  int bid = (blockIdx.x & 7) * 192 + (blockIdx.x >> 3);
  int brow = bid / 12, bc = bid % 12;
  int mat = bc >> 2;  // 0=q,1=k,2=v
  const bf16* W = (mat == 0) ? Wq : (mat == 1) ? Wk : Wv;
  int row0 = brow * 64;
  int col0 = (bc & 3) * 128;

  int tid = threadIdx.x;
  int w = tid >> 6, l = tid & 63;
  int wr = w >> 1, wc = w & 1;
  int g = l >> 4, c = l & 15;
  int lrow = l >> 2;
  int lcol = (l & 3) * 8;
  int arow = tid >> 2;
  int acol = (tid & 3) * 8;

  f32x4 acc[2][4];
  f32x4 zero = {0.f, 0.f, 0.f, 0.f};
#pragma unroll
  for (int m = 0; m < 2; ++m)
#pragma unroll
    for (int n = 0; n < 4; ++n) acc[m][n] = zero;

  *(bf16x8*)(AS(0) + arow * 32 + acol) =
      cvt8(x + (size_t)(row0 + arow) * 512 + acol);
#pragma unroll
  for (int j = 0; j < 2; ++j) {
    int chunk = w * 2 + j;
    gload16(W + (size_t)(col0 + chunk * 16 + lrow) * 512 + lcol,
            BS(0) + chunk * 512);
  }
  __syncthreads();
  int cur = 0;

#pragma unroll 1
  for (int k0 = 0; k0 < 512; k0 += 32) {
    bool more = (k0 < 480);
    f32x4 a0, a1;
    if (more) {
      const f32x4* src =
          (const f32x4*)(x + (size_t)(row0 + arow) * 512 + k0 + 32 + acol);
      a0 = src[0];
      a1 = src[1];
#pragma unroll
      for (int j = 0; j < 2; ++j) {
        int chunk = w * 2 + j;
        gload16(W + (size_t)(col0 + chunk * 16 + lrow) * 512 + k0 + 32 + lcol,
                BS(cur ^ 1) + chunk * 512);
      }
    }
    bf16x8 af[2], bfr[4];
#pragma unroll
    for (int m = 0; m < 2; ++m)
      af[m] = *(const bf16x8*)(AS(cur) + (wr * 32 + m * 16 + c) * 32 + g * 8);
#pragma unroll
    for (int n = 0; n < 4; ++n)
      bfr[n] = *(const bf16x8*)(BS(cur) + (wc * 64 + n * 16 + c) * 32 + g * 8);
#pragma unroll
    for (int m = 0; m < 2; ++m)
#pragma unroll
      for (int n = 0; n < 4; ++n) acc[m][n] = mfma16(af[m], bfr[n], acc[m][n]);
    if (more) {
      *(bf16x8*)(AS(cur ^ 1) + arow * 32 + acol) = pack8(a0, a1);
      __syncthreads();
      cur ^= 1;
    }
  }

  if (mat < 2) {
    bf16* dst = (mat == 0) ? q_ws : k_ws;
    const float esc =
        (mat == 0) ? (0.17677669529663687f * 1.4426950408889634f) : 1.0f;
#pragma unroll
    for (int m = 0; m < 2; ++m) {
      int rbase = row0 + wr * 32 + m * 16 + g * 4;
#pragma unroll
      for (int r = 0; r < 4; ++r) {
        int grow = rbase + r;
        int bb = grow >> 11, s = grow & (S_ - 1);
        float cs = costab[s * 16 + c];
        float sn = sintab[s * 16 + c];
#pragma unroll
        for (int np = 0; np < 2; ++np) {
          int n = np * 2;
          int obase = col0 + wc * 64 + n * 16;
          int h = obase >> 5;
          float a0v = acc[m][n][r], a1v = acc[m][n + 1][r];
          size_t base = (((size_t)bb * H_ + h) * S_ + s) * HD_;
          dst[base + c] = (bf16)((a0v * cs - a1v * sn) * esc);
          dst[base + c + 16] = (bf16)((a1v * cs + a0v * sn) * esc);
        }
      }
    }
  } else {
    __syncthreads();
#pragma unroll
    for (int m = 0; m < 2; ++m) {
#pragma unroll
      for (int n = 0; n < 4; ++n) {
        int o = wc * 64 + n * 16 + c;
        int sb = wr * 32 + m * 16 + g * 4;
        bf16x4 q4;
        q4[0] = (bf16)acc[m][n][0]; q4[1] = (bf16)acc[m][n][1];
        q4[2] = (bf16)acc[m][n][2]; q4[3] = (bf16)acc[m][n][3];
        *(bf16x4*)(&CT[o * 72 + sb]) = q4;
      }
    }
    __syncthreads();
    int o_l = tid >> 1, sh = (tid & 1) * 32;
    int o = col0 + o_l;
    int h = o >> 5, hd = o & 31;
    int bb2 = row0 >> 11, sr = row0 & (S_ - 1);
    size_t dst = (((size_t)bb2 * H_ + h) * HD_ + hd) * S_ + sr + sh;
#pragma unroll
    for (int j = 0; j < 4; ++j)
      *(bf16x8*)(vt_ws + dst + j * 8) =
          *(const bf16x8*)(&CT[o_l * 72 + sh + j * 8]);
  }
#undef AS
#undef BS
#undef CT
}

// ---------------- K2: causal flash attention (fused dual-phase) -------------
// 1024 blocks (bh-XCD swizzle); each block handles BOTH q-tiles (p, 31-p)
// in ONE pass over k-tiles 0..31-p: shared K/V staging (tiles 0..p staged
// once instead of twice), kf/vf LDS fragments loaded once per tile and fed
// to both phases (independent bodies -> 2x ILP on the serial chain).
// Ps reused sequentially by phase A then B (in-wave DS ordering, proven).
// Reader-linear slots + bank-spread staging; Q pre-scaled; ones-MFMA rowsum.
__global__ __launch_bounds__(256) void attn_kernel(
    const bf16* __restrict__ q_ws, const bf16* __restrict__ k_ws,
    const bf16* __restrict__ vt_ws, const int* __restrict__ lengths,
    bf16* __restrict__ ctx_ws) {
  __shared__ __align__(16) bf16 Ks[2][4096];
  __shared__ __align__(16) bf16 Vts[2][4096];
  __shared__ __align__(16) bf16 Ps[4][1024];

  int id = blockIdx.x;            // 0..1023
  int xcd = id & 7;
  int ix = id >> 3;
  int p = ix & 15;
  int bh = xcd + 8 * (ix >> 4);   // all p of this bh share XCD = bh&7
  int bb = bh >> 4, h = bh & 15;
  int tid = threadIdx.x, w = tid >> 6, l = tid & 63, g = l >> 4, c = l & 15;
  const size_t bh_base = ((size_t)bb * H_ + h) * (size_t)S_ * HD_;
  int len = lengths[bb];
  int rowrel = w * 16 + c;

  int qtA = p, qtB = 31 - p;
  int Tu = 32 - p;                // union tile count (>= 17)
  int q0A = qtA * 64 + w * 16, q0B = qtB * 64 + w * 16;

  // staging assignments (bank-spread: write window = l&7)
  int srowK = w * 16 + (l & 15), skgK = l >> 4;
  int srowV = w * 8 + (l & 7), ssgV = l >> 3;
  int slotK8 = (skgK * 16 + (srowK & 15) + ((srowK >> 4) << 6)) * 8;
  int slotV8 =
      ((ssgV & 3) * 16 + (srowV & 15) + (((ssgV >> 2) + ((srowV >> 4) << 1)) << 6)) * 8;

  bf16 one = (bf16)1.0f;
  bf16x8 onesf;
#pragma unroll
  for (int i = 0; i < 8; ++i) onesf[i] = one;

  bf16x8 qfA =
      *(const bf16x8*)(q_ws + bh_base + (size_t)(q0A + c) * HD_ + g * 8);
  bf16x8 qfB =
      *(const bf16x8*)(q_ws + bh_base + (size_t)(q0B + c) * HD_ + g * 8);

  f32x4 zero = {0.f, 0.f, 0.f, 0.f};
  f32x4 ctxaA[2], ctxaB[2];
  ctxaA[0] = zero; ctxaA[1] = zero;
  ctxaB[0] = zero; ctxaB[1] = zero;
  f32x4 lsumA = zero, lsumB = zero;

  const bf16* kbase = k_ws + bh_base + (size_t)srowK * HD_ + skgK * 8;
  const bf16* vbase = vt_ws + bh_base + (size_t)srowV * S_ + ssgV * 8;

  // prologue: stage tiles 0 and 1 (Tu >= 17, both exist)
  bf16x8 rK0 = *(const bf16x8*)kbase;
  bf16x8 rV0 = *(const bf16x8*)vbase;
  bf16x8 rK1 = *(const bf16x8*)(kbase + 64 * HD_);
  bf16x8 rV1 = *(const bf16x8*)(vbase + 64);
  *(bf16x8*)(&Ks[0][slotK8]) = rK0;
  *(bf16x8*)(&Vts[0][slotV8]) = rV0;
  *(bf16x8*)(&Ks[0][2048 + slotK8]) = rK1;
  *(bf16x8*)(&Vts[0][2048 + slotV8]) = rV1;
  __syncthreads();
  int cur = 0;

  auto body = [&](int qt, const bf16x8& qf, f32x4* ctxa, f32x4& lsum, int t,
                  const bf16x8(&kf)[4], const bf16x8(&vf)[4]) {
    // swapped QK^T : sacc[n][r] = P[q][j = t*64 + n*16 + g*4 + r]
    f32x4 sacc[4];
#pragma unroll
    for (int n = 0; n < 4; ++n) sacc[n] = mfma16(kf[n], qf, zero);

    float sv[4][4];
    if (t != qt) {
#pragma unroll
      for (int n = 0; n < 4; ++n)
#pragma unroll
        for (int r = 0; r < 4; ++r)
          sv[n][r] = __builtin_amdgcn_exp2f(sacc[n][r]);
    } else {
#pragma unroll
      for (int n = 0; n < 4; ++n) {
        int jr = n * 16 + g * 4;
#pragma unroll
        for (int r = 0; r < 4; ++r) {
          float e = __builtin_amdgcn_exp2f(sacc[n][r]);
          sv[n][r] = (jr + r > rowrel) ? 0.f : e;
        }
      }
    }

    // P -> per-wave LDS, reader-linear slots (reused by both phases)
#pragma unroll
    for (int n = 0; n < 4; ++n) {
      bf16x4 pk;
      pk[0] = (bf16)sv[n][0]; pk[1] = (bf16)sv[n][1];
      pk[2] = (bf16)sv[n][2]; pk[3] = (bf16)sv[n][3];
      int chunk = 2 * n + (g >> 1);
      int poff = ((chunk >> 2) << 9) + ((chunk & 3) * 16 + c) * 8 + ((g & 1) << 2);
      *(bf16x4*)(&Ps[w][poff]) = pk;
    }

    bf16x8 pf0 = *(const bf16x8*)(&Ps[w][l * 8]);
    bf16x8 pf1 = *(const bf16x8*)(&Ps[w][512 + l * 8]);

    lsum = mfma16(pf0, onesf, lsum);
    lsum = mfma16(pf1, onesf, lsum);

#pragma unroll
    for (int n2 = 0; n2 < 2; ++n2) {
      ctxa[n2] = mfma16(pf0, vf[2 * n2], ctxa[n2]);
      ctxa[n2] = mfma16(pf1, vf[2 * n2 + 1], ctxa[n2]);
    }
  };

  auto tile = [&](int t, int off) {
    const bf16* KsC = &Ks[cur][off];
    const bf16* VtsC = &Vts[cur][off];
    bf16x8 kf[4], vf[4];
#pragma unroll
    for (int k = 0; k < 4; ++k) {
      kf[k] = *(const bf16x8*)(&KsC[(l + (k << 6)) * 8]);
      vf[k] = *(const bf16x8*)(&VtsC[(l + (k << 6)) * 8]);
    }
    if (t <= qtA) body(qtA, qfA, ctxaA, lsumA, t, kf, vf);
    body(qtB, qfB, ctxaB, lsumB, t, kf, vf);  // t <= qtB always (t < Tu)
  };

#pragma unroll 1
  for (int r = 0;; ++r) {
    int t0 = 2 * r, t1 = t0 + 1;
    bool more = (t0 + 2 < Tu);
    if (more) {  // prefetch next pair (over-read of last+1 tile is benign)
      const bf16* kp = kbase + (size_t)(t0 + 2) * 64 * HD_;
      const bf16* vp = vbase + (t0 + 2) * 64;
      rK0 = *(const bf16x8*)kp;
      rV0 = *(const bf16x8*)vp;
      rK1 = *(const bf16x8*)(kp + 64 * HD_);
      rV1 = *(const bf16x8*)(vp + 64);
    }
    tile(t0, 0);
    if (t1 < Tu) tile(t1, 2048);
    if (!more) break;
    *(bf16x8*)(&Ks[cur ^ 1][slotK8]) = rK0;
    *(bf16x8*)(&Vts[cur ^ 1][slotV8]) = rV0;
    *(bf16x8*)(&Ks[cur ^ 1][2048 + slotK8]) = rK1;
    *(bf16x8*)(&Vts[cur ^ 1][2048 + slotV8]) = rV1;
    __syncthreads();
    cur ^= 1;
  }

  // epilogues: lsum[r] = rowsum[q0+g*4+r] (ctxa D-layout)
#pragma unroll
  for (int n = 0; n < 2; ++n)
#pragma unroll
    for (int r = 0; r < 4; ++r) {
      int qr = q0A + g * 4 + r;
      float val = ctxaA[n][r] / lsumA[r];
      if (qr >= len) val = 0.f;
      ctx_ws[(((size_t)bb * S_ + qr) * H_ + h) * HD_ + n * 16 + c] = (bf16)val;
    }
#pragma unroll
  for (int n = 0; n < 2; ++n)
#pragma unroll
    for (int r = 0; r < 4; ++r) {
      int qr = q0B + g * 4 + r;
      float val = ctxaB[n][r] / lsumB[r];
      if (qr >= len) val = 0.f;
      ctx_ws[(((size_t)bb * S_ + qr) * H_ + h) * HD_ + n * 16 + c] = (bf16)val;
    }
}

// ---------------- K3: output projection (BM=64, XCD swizzle, f32 out) -------
__global__ __launch_bounds__(256) void out_proj_kernel(
    const bf16* __restrict__ ctx, const bf16* __restrict__ Wo,
    float* __restrict__ out) {
  __shared__ __align__(16) bf16 As[2][2048];  // 64x32 tile
  __shared__ __align__(16) bf16 Bs[2][4096];  // 128x32 tile

  int bid = (blockIdx.x & 7) * 64 + (blockIdx.x >> 3);
  int brow = bid >> 2, bc = bid & 3;
  int row0 = brow * 64, col0 = bc * 128;
  int tid = threadIdx.x;
  int w = tid >> 6, l = tid & 63;
  int wr = w >> 1, wc = w & 1;
  int g = l >> 4, c = l & 15;
  int lrow = l >> 2;
  int lcol = (l & 3) * 8;

  f32x4 acc[2][4];
  f32x4 zero = {0.f, 0.f, 0.f, 0.f};
#pragma unroll
  for (int m = 0; m < 2; ++m)
#pragma unroll
    for (int n = 0; n < 4; ++n) acc[m][n] = zero;

#pragma unroll
  for (int j = 0; j < 3; ++j) {
    int chunk = w * 3 + j;
    if (chunk < 4)
      gload16(ctx + (size_t)(row0 + chunk * 16 + lrow) * 512 + lcol,
              As[0] + chunk * 512);
    else
      gload16(Wo + (size_t)(col0 + (chunk - 4) * 16 + lrow) * 512 + lcol,
              Bs[0] + (chunk - 4) * 512);
  }
  __syncthreads();
  int cur = 0;

#pragma unroll 1
  for (int k0 = 0; k0 < 512; k0 += 32) {
    bool more = (k0 < 480);
    if (more) {
#pragma unroll
      for (int j = 0; j < 3; ++j) {
        int chunk = w * 3 + j;
        if (chunk < 4)
          gload16(ctx + (size_t)(row0 + chunk * 16 + lrow) * 512 + k0 + 32 + lcol,
                  As[cur ^ 1] + chunk * 512);
        else
          gload16(Wo + (size_t)(col0 + (chunk - 4) * 16 + lrow) * 512 + k0 + 32 +
                      lcol,
                  Bs[cur ^ 1] + (chunk - 4) * 512);
      }
    }
    bf16x8 af[2], bfr[4];
#pragma unroll
    for (int m = 0; m < 2; ++m)
      af[m] = *(const bf16x8*)(As[cur] + (wr * 32 + m * 16 + c) * 32 + g * 8);
#pragma unroll
    for (int n = 0; n < 4; ++n)
      bfr[n] = *(const bf16x8*)(Bs[cur] + (wc * 64 + n * 16 + c) * 32 + g * 8);
#pragma unroll
    for (int m = 0; m < 2; ++m)
#pragma unroll
      for (int n = 0; n < 4; ++n) acc[m][n] = mfma16(af[m], bfr[n], acc[m][n]);
    if (more) {
      __syncthreads();
      cur ^= 1;
    }
  }

#pragma unroll
  for (int m = 0; m < 2; ++m) {
    int rbase = row0 + wr * 32 + m * 16 + g * 4;
#pragma unroll
    for (int n = 0; n < 4; ++n) {
      int o = col0 + wc * 64 + n * 16 + c;
#pragma unroll
      for (int r = 0; r < 4; ++r)
        out[(size_t)(rbase + r) * 512 + o] = acc[m][n][r];
    }
  }
}

extern "C" void kernel_launch(void* const* d_in, const int* in_sizes, int n_in,
                              void* d_out, int out_size, void* d_ws,
                              size_t ws_size, hipStream_t stream) {
  const float* x = (const float*)d_in[0];
  const unsigned char* am = (const unsigned char*)d_in[1];
  const unsigned char* kpm = (const unsigned char*)d_in[2];
  const float* Wq = (const float*)d_in[3];
  const float* Wk = (const float*)d_in[4];
  const float* Wv = (const float*)d_in[5];
  const float* Wo = (const float*)d_in[6];
  float* out = (float*)d_out;

  char* ws = (char*)d_ws;
  int* lengths = (int*)ws;
  const size_t QKV_ELEMS = (size_t)B_ * H_ * S_ * HD_;
  const size_t W_ELEMS = (size_t)D_ * D_;
  bf16* ctx_ws = (bf16*)(ws + 256);  // 8 MB
  bf16* q_ws = ctx_ws + QKV_ELEMS;
  bf16* k_ws = q_ws + QKV_ELEMS;
  bf16* vt_ws = k_ws + QKV_ELEMS;
  bf16* wqb = vt_ws + QKV_ELEMS;
  bf16* wkb = wqb + W_ELEMS;
  bf16* wvb = wkb + W_ELEMS;
  bf16* wob = wvb + W_ELEMS;
  float* costab = (float*)(wob + W_ELEMS);
  float* sintab = costab + (size_t)S_ * 16;

  hipLaunchKernelGGL(prep_kernel, dim3(641), dim3(256), 0, stream, Wq, Wk, Wv,
                     Wo, am, kpm, wqb, wkb, wvb, wob, lengths, costab, sintab);
  hipLaunchKernelGGL(qkv_rope_kernel, dim3(1536), dim3(256), 0, stream, x, wqb,
                     wkb, wvb, costab, sintab, q_ws, k_ws, vt_ws);
  hipLaunchKernelGGL(attn_kernel, dim3(1024), dim3(256), 0, stream, q_ws, k_ws,
                     vt_ws, lengths, ctx_ws);
  hipLaunchKernelGGL(out_proj_kernel, dim3(512), dim3(256), 0, stream, ctx_ws,
                     wob, out);
}

// Round 25
// 108.827 us; speedup vs baseline: 1.0549x; 1.0549x over previous
//
#include <hip/hip_runtime.h>
#include <hip/hip_bf16.h>

#define B_ 4
#define S_ 2048
#define D_ 512
#define H_ 16
#define HD_ 32

typedef __bf16 bf16;
typedef __bf16 bf16x4 __attribute__((ext_vector_type(4)));
typedef __bf16 bf16x8 __attribute__((ext_vector_type(8)));
typedef float f32x4 __attribute__((ext_vector_type(4)));

__device__ __forceinline__ f32x4 mfma16(bf16x8 a, bf16x8 b, f32x4 c) {
  return __builtin_amdgcn_mfma_f32_16x16x32_bf16(a, b, c, 0, 0, 0);
}

// async global->LDS, 16B per lane; lds dest wave-uniform base (HW: +lane*16)
__device__ __forceinline__ void gload16(const bf16* g, bf16* l) {
  __builtin_amdgcn_global_load_lds(
      (const __attribute__((address_space(1))) void*)g,
      (__attribute__((address_space(3))) void*)l, 16, 0, 0);
}

__device__ __forceinline__ bf16x8 cvt8(const float* __restrict__ p) {
  const f32x4* v = (const f32x4*)p;
  f32x4 a = v[0], b = v[1];
  bf16x8 r;
  r[0] = (bf16)a[0]; r[1] = (bf16)a[1]; r[2] = (bf16)a[2]; r[3] = (bf16)a[3];
  r[4] = (bf16)b[0]; r[5] = (bf16)b[1]; r[6] = (bf16)b[2]; r[7] = (bf16)b[3];
  return r;
}

__device__ __forceinline__ bf16x8 pack8(f32x4 a, f32x4 b) {
  bf16x8 r;
  r[0] = (bf16)a[0]; r[1] = (bf16)a[1]; r[2] = (bf16)a[2]; r[3] = (bf16)a[3];
  r[4] = (bf16)b[0]; r[5] = (bf16)b[1]; r[6] = (bf16)b[2]; r[7] = (bf16)b[3];
  return r;
}

// ------- K0: prep (cvt_w + lengths + RoPE cos/sin table; x stays f32) -------
__global__ __launch_bounds__(256) void prep_kernel(
    const float* __restrict__ wq, const float* __restrict__ wk,
    const float* __restrict__ wv, const float* __restrict__ wo,
    const unsigned char* __restrict__ am, const unsigned char* __restrict__ kpm,
    bf16* __restrict__ dq, bf16* __restrict__ dk, bf16* __restrict__ dv,
    bf16* __restrict__ dwo, int* __restrict__ lengths_out,
    float* __restrict__ costab, float* __restrict__ sintab) {
  int bid = blockIdx.x;
  if (bid < 512) {  // weights: 128 blocks per 512x512 matrix
    int mat = bid >> 7;
    size_t i = (size_t)(bid & 127) * 256 + threadIdx.x;
    const float* s = (mat == 0) ? wq : (mat == 1) ? wk : (mat == 2) ? wv : wo;
    bf16* d = (mat == 0) ? dq : (mat == 1) ? dk : (mat == 2) ? dv : dwo;
    *(bf16x8*)(d + i * 8) = cvt8(s + i * 8);
  } else if (bid == 512) {  // lengths: 4 waves, wave b handles batch b
    int b = threadIdx.x >> 6, lane = threadIdx.x & 63;
    int esize;
    if (am[1] == 1) esize = 1;
    else if (am[2] == 0x80 && am[3] == 0x3F) esize = 2;
    else if (am[3] == 0x3C) esize = 2;
    else if (am[4] == 1) esize = 4;
    else if (am[6] == 0x80 && am[7] == 0x3F) esize = 4;
    else if (am[8] == 1) esize = 8;
    else esize = 1;
    int cnt = 0;
    for (int i = lane; i < S_; i += 64) {
      size_t off = ((size_t)b * S_ + i) * (size_t)esize;
      unsigned char nz = 0;
      for (int e = 0; e < esize; ++e) nz |= kpm[off + e];
      cnt += (nz == 0) ? 1 : 0;
    }
    for (int off = 1; off < 64; off <<= 1) cnt += __shfl_xor(cnt, off);
    if (lane == 0) lengths_out[b] = cnt;
  } else {  // RoPE table: [S][16] cos + sin (128 blocks)
    int ti = (bid - 513) * 256 + threadIdx.x;  // < 32768
    int s = ti >> 4, cc = ti & 15;
    float invf = powf(10000.0f, -(float)cc * (1.0f / 16.0f));
    float ang = (float)s * invf;
    costab[ti] = cosf(ang);
    sintab[ti] = sinf(ang);
  }
}

// ---------------- K1: fused QKV GEMM + RoPE (BM=64, 1536 blocks) ------------
__global__ __launch_bounds__(256) void qkv_rope_kernel(
    const float* __restrict__ x, const bf16* __restrict__ Wq,
    const bf16* __restrict__ Wk, const bf16* __restrict__ Wv,
    const float* __restrict__ costab, const float* __restrict__ sintab,
    bf16* __restrict__ q_ws, bf16* __restrict__ k_ws, bf16* __restrict__ vt_ws) {
  __shared__ __align__(16) bf16 smem[12288];  // 24576 B
#define AS(b) (smem + (b) * 2048)            // 64x32 A tile
#define BS(b) (smem + 4096 + (b) * 4096)     // 128x32 B tile
#define CT smem                              // V transpose: 128x72

  int bid = (blockIdx.x & 7) * 192 + (blockIdx.x >> 3);
  int brow = bid / 12, bc = bid % 12;
  int mat = bc >> 2;  // 0=q,1=k,2=v
  const bf16* W = (mat == 0) ? Wq : (mat == 1) ? Wk : Wv;
  int row0 = brow * 64;
  int col0 = (bc & 3) * 128;

  int tid = threadIdx.x;
  int w = tid >> 6, l = tid & 63;
  int wr = w >> 1, wc = w & 1;
  int g = l >> 4, c = l & 15;
  int lrow = l >> 2;
  int lcol = (l & 3) * 8;
  int arow = tid >> 2;
  int acol = (tid & 3) * 8;

  f32x4 acc[2][4];
  f32x4 zero = {0.f, 0.f, 0.f, 0.f};
#pragma unroll
  for (int m = 0; m < 2; ++m)
#pragma unroll
    for (int n = 0; n < 4; ++n) acc[m][n] = zero;

  *(bf16x8*)(AS(0) + arow * 32 + acol) =
      cvt8(x + (size_t)(row0 + arow) * 512 + acol);
#pragma unroll
  for (int j = 0; j < 2; ++j) {
    int chunk = w * 2 + j;
    gload16(W + (size_t)(col0 + chunk * 16 + lrow) * 512 + lcol,
            BS(0) + chunk * 512);
  }
  __syncthreads();
  int cur = 0;

#pragma unroll 1
  for (int k0 = 0; k0 < 512; k0 += 32) {
    bool more = (k0 < 480);
    f32x4 a0, a1;
    if (more) {
      const f32x4* src =
          (const f32x4*)(x + (size_t)(row0 + arow) * 512 + k0 + 32 + acol);
      a0 = src[0];
      a1 = src[1];
#pragma unroll
      for (int j = 0; j < 2; ++j) {
        int chunk = w * 2 + j;
        gload16(W + (size_t)(col0 + chunk * 16 + lrow) * 512 + k0 + 32 + lcol,
                BS(cur ^ 1) + chunk * 512);
      }
    }
    bf16x8 af[2], bfr[4];
#pragma unroll
    for (int m = 0; m < 2; ++m)
      af[m] = *(const bf16x8*)(AS(cur) + (wr * 32 + m * 16 + c) * 32 + g * 8);
#pragma unroll
    for (int n = 0; n < 4; ++n)
      bfr[n] = *(const bf16x8*)(BS(cur) + (wc * 64 + n * 16 + c) * 32 + g * 8);
#pragma unroll
    for (int m = 0; m < 2; ++m)
#pragma unroll
      for (int n = 0; n < 4; ++n) acc[m][n] = mfma16(af[m], bfr[n], acc[m][n]);
    if (more) {
      *(bf16x8*)(AS(cur ^ 1) + arow * 32 + acol) = pack8(a0, a1);
      __syncthreads();
      cur ^= 1;
    }
  }

  if (mat < 2) {
    bf16* dst = (mat == 0) ? q_ws : k_ws;
    const float esc =
        (mat == 0) ? (0.17677669529663687f * 1.4426950408889634f) : 1.0f;
#pragma unroll
    for (int m = 0; m < 2; ++m) {
      int rbase = row0 + wr * 32 + m * 16 + g * 4;
#pragma unroll
      for (int r = 0; r < 4; ++r) {
        int grow = rbase + r;
        int bb = grow >> 11, s = grow & (S_ - 1);
        float cs = costab[s * 16 + c];
        float sn = sintab[s * 16 + c];
#pragma unroll
        for (int np = 0; np < 2; ++np) {
          int n = np * 2;
          int obase = col0 + wc * 64 + n * 16;
          int h = obase >> 5;
          float a0v = acc[m][n][r], a1v = acc[m][n + 1][r];
          size_t base = (((size_t)bb * H_ + h) * S_ + s) * HD_;
          dst[base + c] = (bf16)((a0v * cs - a1v * sn) * esc);
          dst[base + c + 16] = (bf16)((a1v * cs + a0v * sn) * esc);
        }
      }
    }
  } else {
    __syncthreads();
#pragma unroll
    for (int m = 0; m < 2; ++m) {
#pragma unroll
      for (int n = 0; n < 4; ++n) {
        int o = wc * 64 + n * 16 + c;
        int sb = wr * 32 + m * 16 + g * 4;
        bf16x4 q4;
        q4[0] = (bf16)acc[m][n][0]; q4[1] = (bf16)acc[m][n][1];
        q4[2] = (bf16)acc[m][n][2]; q4[3] = (bf16)acc[m][n][3];
        *(bf16x4*)(&CT[o * 72 + sb]) = q4;
      }
    }
    __syncthreads();
    int o_l = tid >> 1, sh = (tid & 1) * 32;
    int o = col0 + o_l;
    int h = o >> 5, hd = o & 31;
    int bb2 = row0 >> 11, sr = row0 & (S_ - 1);
    size_t dst = (((size_t)bb2 * H_ + h) * HD_ + hd) * S_ + sr + sh;
#pragma unroll
    for (int j = 0; j < 4; ++j)
      *(bf16x8*)(vt_ws + dst + j * 8) =
          *(const bf16x8*)(&CT[o_l * 72 + sh + j * 8]);
  }
#undef AS
#undef BS
#undef CT
}

// ---------------- K2: causal flash attention (r23: paired-tile rounds) ------
// 1024 blocks (bh-XCD swizzle); block handles q-tiles p then 31-p
// sequentially. 2 k-tiles per barrier round; reader-linear slots +
// bank-spread staging; Q pre-scaled; ones-MFMA rowsum.
__global__ __launch_bounds__(256) void attn_kernel(
    const bf16* __restrict__ q_ws, const bf16* __restrict__ k_ws,
    const bf16* __restrict__ vt_ws, const int* __restrict__ lengths,
    bf16* __restrict__ ctx_ws) {
  __shared__ __align__(16) bf16 Ks[2][4096];
  __shared__ __align__(16) bf16 Vts[2][4096];
  __shared__ __align__(16) bf16 Ps[4][1024];

  int id = blockIdx.x;            // 0..1023
  int xcd = id & 7;
  int ix = id >> 3;               // 0..127
  int p = ix & 15;                // q-tile pair
  int bh = xcd + 8 * (ix >> 4);   // all p of this bh share XCD = bh&7
  int bb = bh >> 4, h = bh & 15;
  int tid = threadIdx.x, w = tid >> 6, l = tid & 63, g = l >> 4, c = l & 15;
  const size_t bh_base = ((size_t)bb * H_ + h) * (size_t)S_ * HD_;
  int len = lengths[bb];
  int rowrel = w * 16 + c;

  // staging assignments (bank-spread: write window = l&7)
  int srowK = w * 16 + (l & 15), skgK = l >> 4;
  int srowV = w * 8 + (l & 7), ssgV = l >> 3;
  int slotK8 = (skgK * 16 + (srowK & 15) + ((srowK >> 4) << 6)) * 8;
  int slotV8 =
      ((ssgV & 3) * 16 + (srowV & 15) + (((ssgV >> 2) + ((srowV >> 4) << 1)) << 6)) * 8;

  bf16 one = (bf16)1.0f;
  bf16x8 onesf;
#pragma unroll
  for (int i = 0; i < 8; ++i) onesf[i] = one;

#pragma unroll 1
  for (int phase = 0; phase < 2; ++phase) {
    int qt = phase ? (31 - p) : p;
    int q0 = qt * 64 + w * 16;
    int T = qt + 1;

    bf16x8 qf = *(const bf16x8*)(q_ws + bh_base + (size_t)(q0 + c) * HD_ + g * 8);

    f32x4 zero = {0.f, 0.f, 0.f, 0.f};
    f32x4 ctxa[2];
    ctxa[0] = zero; ctxa[1] = zero;
    f32x4 lsum = zero;

    const bf16* kbase = k_ws + bh_base + (size_t)srowK * HD_ + skgK * 8;
    const bf16* vbase = vt_ws + bh_base + (size_t)srowV * S_ + ssgV * 8;

    // prologue: tiles 0 and 1
    bf16x8 rK0 = *(const bf16x8*)kbase;
    bf16x8 rV0 = *(const bf16x8*)vbase;
    bf16x8 rK1 = rK0, rV1 = rV0;
    if (T > 1) {
      rK1 = *(const bf16x8*)(kbase + 64 * HD_);
      rV1 = *(const bf16x8*)(vbase + 64);
    }
    __syncthreads();  // previous phase's readers done with buffers
    *(bf16x8*)(&Ks[0][slotK8]) = rK0;
    *(bf16x8*)(&Vts[0][slotV8]) = rV0;
    *(bf16x8*)(&Ks[0][2048 + slotK8]) = rK1;
    *(bf16x8*)(&Vts[0][2048 + slotV8]) = rV1;
    __syncthreads();
    int cur = 0;

    auto body = [&](int t, int off) {
      const bf16* KsC = &Ks[cur][off];
      const bf16* VtsC = &Vts[cur][off];
      // swapped QK^T : sacc[n][r] = P[q=q0+c][j=t*64+n*16+g*4+r]
      f32x4 sacc[4];
#pragma unroll
      for (int n = 0; n < 4; ++n) {
        bf16x8 kf = *(const bf16x8*)(&KsC[(l + (n << 6)) * 8]);
        sacc[n] = mfma16(kf, qf, zero);
      }

      float sv[4][4];
      if (t != qt) {
#pragma unroll
        for (int n = 0; n < 4; ++n)
#pragma unroll
          for (int r = 0; r < 4; ++r)
            sv[n][r] = __builtin_amdgcn_exp2f(sacc[n][r]);
      } else {
#pragma unroll
        for (int n = 0; n < 4; ++n) {
          int jr = n * 16 + g * 4;
#pragma unroll
          for (int r = 0; r < 4; ++r) {
            float e = __builtin_amdgcn_exp2f(sacc[n][r]);
            sv[n][r] = (jr + r > rowrel) ? 0.f : e;
          }
        }
      }

      // P -> per-wave LDS, reader-linear slots
#pragma unroll
      for (int n = 0; n < 4; ++n) {
        bf16x4 pk;
        pk[0] = (bf16)sv[n][0]; pk[1] = (bf16)sv[n][1];
        pk[2] = (bf16)sv[n][2]; pk[3] = (bf16)sv[n][3];
        int chunk = 2 * n + (g >> 1);
        int poff = ((chunk >> 2) << 9) + ((chunk & 3) * 16 + c) * 8 + ((g & 1) << 2);
        *(bf16x4*)(&Ps[w][poff]) = pk;
      }

      bf16x8 pf0 = *(const bf16x8*)(&Ps[w][l * 8]);
      bf16x8 pf1 = *(const bf16x8*)(&Ps[w][512 + l * 8]);

      // row-sum via ones-MFMA (same D-layout as ctxa)
      lsum = mfma16(pf0, onesf, lsum);
      lsum = mfma16(pf1, onesf, lsum);

#pragma unroll
      for (int n2 = 0; n2 < 2; ++n2) {
        bf16x8 v0 = *(const bf16x8*)(&VtsC[(l + ((2 * n2) << 6)) * 8]);
        bf16x8 v1 = *(const bf16x8*)(&VtsC[(l + ((1 + 2 * n2) << 6)) * 8]);
        ctxa[n2] = mfma16(pf0, v0, ctxa[n2]);
        ctxa[n2] = mfma16(pf1, v1, ctxa[n2]);
      }
    };

#pragma unroll 1
    for (int r = 0;; ++r) {
      int t0 = 2 * r, t1 = 2 * r + 1;
      bool more = (t0 + 2 < T);
      if (more) {  // prefetch next pair (over-read of last+1 tile is benign)
        const bf16* kp = kbase + (size_t)(t0 + 2) * 64 * HD_;
        const bf16* vp = vbase + (t0 + 2) * 64;
        rK0 = *(const bf16x8*)kp;
        rV0 = *(const bf16x8*)vp;
        rK1 = *(const bf16x8*)(kp + 64 * HD_);
        rV1 = *(const bf16x8*)(vp + 64);
      }
      body(t0, 0);
      if (t1 < T) body(t1, 2048);
      if (!more) break;
      *(bf16x8*)(&Ks[cur ^ 1][slotK8]) = rK0;
      *(bf16x8*)(&Vts[cur ^ 1][slotV8]) = rV0;
      *(bf16x8*)(&Ks[cur ^ 1][2048 + slotK8]) = rK1;
      *(bf16x8*)(&Vts[cur ^ 1][2048 + slotV8]) = rV1;
      __syncthreads();
      cur ^= 1;
    }

    // epilogue: lsum[r] already = rowsum[q0+g*4+r]
#pragma unroll
    for (int n = 0; n < 2; ++n)
#pragma unroll
      for (int r = 0; r < 4; ++r) {
        int qr = q0 + g * 4 + r;
        float val = ctxa[n][r] / lsum[r];
        if (qr >= len) val = 0.f;
        ctx_ws[(((size_t)bb * S_ + qr) * H_ + h) * HD_ + n * 16 + c] = (bf16)val;
      }
  }
}

// ---------------- K3: output projection (BM=64, XCD swizzle, f32 out) -------
__global__ __launch_bounds__(256) void out_proj_kernel(
    const bf16* __restrict__ ctx, const bf16* __restrict__ Wo,
    float* __restrict__ out) {
  __shared__ __align__(16) bf16 As[2][2048];  // 64x32 tile
  __shared__ __align__(16) bf16 Bs[2][4096];  // 128x32 tile

  int bid = (blockIdx.x & 7) * 64 + (blockIdx.x >> 3);
  int brow = bid >> 2, bc = bid & 3;
  int row0 = brow * 64, col0 = bc * 128;
  int tid = threadIdx.x;
  int w = tid >> 6, l = tid & 63;
  int wr = w >> 1, wc = w & 1;
  int g = l >> 4, c = l & 15;
  int lrow = l >> 2;
  int lcol = (l & 3) * 8;

  f32x4 acc[2][4];
  f32x4 zero = {0.f, 0.f, 0.f, 0.f};
#pragma unroll
  for (int m = 0; m < 2; ++m)
#pragma unroll
    for (int n = 0; n < 4; ++n) acc[m][n] = zero;

#pragma unroll
  for (int j = 0; j < 3; ++j) {
    int chunk = w * 3 + j;
    if (chunk < 4)
      gload16(ctx + (size_t)(row0 + chunk * 16 + lrow) * 512 + lcol,
              As[0] + chunk * 512);
    else
      gload16(Wo + (size_t)(col0 + (chunk - 4) * 16 + lrow) * 512 + lcol,
              Bs[0] + (chunk - 4) * 512);
  }
  __syncthreads();
  int cur = 0;

#pragma unroll 1
  for (int k0 = 0; k0 < 512; k0 += 32) {
    bool more = (k0 < 480);
    if (more) {
#pragma unroll
      for (int j = 0; j < 3; ++j) {
        int chunk = w * 3 + j;
        if (chunk < 4)
          gload16(ctx + (size_t)(row0 + chunk * 16 + lrow) * 512 + k0 + 32 + lcol,
                  As[cur ^ 1] + chunk * 512);
        else
          gload16(Wo + (size_t)(col0 + (chunk - 4) * 16 + lrow) * 512 + k0 + 32 +
                      lcol,
                  Bs[cur ^ 1] + (chunk - 4) * 512);
      }
    }
    bf16x8 af[2], bfr[4];
#pragma unroll
    for (int m = 0; m < 2; ++m)
      af[m] = *(const bf16x8*)(As[cur] + (wr * 32 + m * 16 + c) * 32 + g * 8);
#pragma unroll
    for (int n = 0; n < 4; ++n)
      bfr[n] = *(const bf16x8*)(Bs[cur] + (wc * 64 + n * 16 + c) * 32 + g * 8);
#pragma unroll
    for (int m = 0; m < 2; ++m)
#pragma unroll
      for (int n = 0; n < 4; ++n) acc[m][n] = mfma16(af[m], bfr[n], acc[m][n]);
    if (more) {
      __syncthreads();
      cur ^= 1;
    }
  }

#pragma unroll
  for (int m = 0; m < 2; ++m) {
    int rbase = row0 + wr * 32 + m * 16 + g * 4;
#pragma unroll
    for (int n = 0; n < 4; ++n) {
      int o = col0 + wc * 64 + n * 16 + c;
#pragma unroll
      for (int r = 0; r < 4; ++r)
        out[(size_t)(rbase + r) * 512 + o] = acc[m][n][r];
    }
  }
}

extern "C" void kernel_launch(void* const* d_in, const int* in_sizes, int n_in,
                              void* d_out, int out_size, void* d_ws,
                              size_t ws_size, hipStream_t stream) {
  const float* x = (const float*)d_in[0];
  const unsigned char* am = (const unsigned char*)d_in[1];
  const unsigned char* kpm = (const unsigned char*)d_in[2];
  const float* Wq = (const float*)d_in[3];
  const float* Wk = (const float*)d_in[4];
  const float* Wv = (const float*)d_in[5];
  const float* Wo = (const float*)d_in[6];
  float* out = (float*)d_out;

  char* ws = (char*)d_ws;
  int* lengths = (int*)ws;
  const size_t QKV_ELEMS = (size_t)B_ * H_ * S_ * HD_;
  const size_t W_ELEMS = (size_t)D_ * D_;
  bf16* ctx_ws = (bf16*)(ws + 256);  // 8 MB
  bf16* q_ws = ctx_ws + QKV_ELEMS;
  bf16* k_ws = q_ws + QKV_ELEMS;
  bf16* vt_ws = k_ws + QKV_ELEMS;
  bf16* wqb = vt_ws + QKV_ELEMS;
  bf16* wkb = wqb + W_ELEMS;
  bf16* wvb = wkb + W_ELEMS;
  bf16* wob = wvb + W_ELEMS;
  float* costab = (float*)(wob + W_ELEMS);
  float* sintab = costab + (size_t)S_ * 16;

  hipLaunchKernelGGL(prep_kernel, dim3(641), dim3(256), 0, stream, Wq, Wk, Wv,
                     Wo, am, kpm, wqb, wkb, wvb, wob, lengths, costab, sintab);
  hipLaunchKernelGGL(qkv_rope_kernel, dim3(1536), dim3(256), 0, stream, x, wqb,
                     wkb, wvb, costab, sintab, q_ws, k_ws, vt_ws);
  hipLaunchKernelGGL(attn_kernel, dim3(1024), dim3(256), 0, stream, q_ws, k_ws,
                     vt_ws, lengths, ctx_ws);
  hipLaunchKernelGGL(out_proj_kernel, dim3(512), dim3(256), 0, stream, ctx_ws,
                     wob, out);
}